// Round 1
// baseline (130.756 us; speedup 1.0000x reference)
//
#include <hip/hip_runtime.h>
#include <math.h>

// Problem constants (from reference): B=4, S=2048, D_IN=1024, D_OUT=1024, E=8, K=2
#define TOKENS 8192
#define DIN    1024
#define DOUT   1024
#define NE     8

// Butterfly reduction across the 64-lane wave; every lane ends with the full sum.
__device__ __forceinline__ float wredsum(float v) {
#pragma unroll
  for (int off = 32; off > 0; off >>= 1) v += __shfl_xor(v, off, 64);
  return v;
}

// One wave handles TWO tokens (t0, t1) so each LDS/global weight read feeds 2 FMAs.
// Grid: 1024 blocks x 256 threads = 4096 waves = 8192 tokens. Exact cover.
__global__ __launch_bounds__(256, 4) void moe_fused(
    const float* __restrict__ x,             // [TOKENS][DIN]
    const float* __restrict__ gate_w,        // [NE][DIN]
    const float* __restrict__ gate_b,        // [NE]
    const float* __restrict__ expert_biases, // [NE]
    const float* __restrict__ expert_w,      // [NE][DOUT][DIN]
    const float* __restrict__ expert_b,      // [NE][DOUT]
    float* __restrict__ out,                 // [TOKENS][DOUT]
    float* __restrict__ out_idx) {           // [TOKENS][2] (indices as f32)
  // ---- stage gate_w into LDS (32 KB) ----
  __shared__ float lgate[NE * DIN];
  {
    const float4* src = (const float4*)gate_w;
    float4* dst = (float4*)lgate;
#pragma unroll
    for (int i = 0; i < (NE * DIN / 4) / 256; ++i)
      dst[threadIdx.x + i * 256] = src[threadIdx.x + i * 256];
  }
  __syncthreads();

  const int wave = blockIdx.x * 4 + (threadIdx.x >> 6);
  const int lane = threadIdx.x & 63;
  const int t0 = wave * 2;
  const int t1 = t0 + 1;

  // ---- load x rows for both tokens (coalesced float4, 16 floats/lane) ----
  float4 xa[4], xb[4];
  const float4* xr0 = (const float4*)(x + (size_t)t0 * DIN);
  const float4* xr1 = (const float4*)(x + (size_t)t1 * DIN);
#pragma unroll
  for (int i = 0; i < 4; ++i) {
    xa[i] = xr0[lane + 64 * i];
    xb[i] = xr1[lane + 64 * i];
  }

  // ---- gate logits: 8 dots per token against LDS-resident gate_w ----
  float za[NE], zb[NE];
#pragma unroll
  for (int e = 0; e < NE; ++e) { za[e] = 0.f; zb[e] = 0.f; }
#pragma unroll
  for (int e = 0; e < NE; ++e) {
    const float4* wr = (const float4*)(lgate + e * DIN);
#pragma unroll
    for (int i = 0; i < 4; ++i) {
      float4 w = wr[lane + 64 * i];
      za[e] += xa[i].x * w.x + xa[i].y * w.y + xa[i].z * w.z + xa[i].w * w.w;
      zb[e] += xb[i].x * w.x + xb[i].y * w.y + xb[i].z * w.z + xb[i].w * w.w;
    }
  }
#pragma unroll
  for (int e = 0; e < NE; ++e) {
    float bias = gate_b[e] + expert_biases[e];
    za[e] = wredsum(za[e]) + bias;
    zb[e] = wredsum(zb[e]) + bias;
  }

  // ---- top-2 on logits (sigmoid is monotone -> same indices, stable ties) ----
  int e0a = 0; float z0a = za[0];
#pragma unroll
  for (int e = 1; e < NE; ++e) if (za[e] > z0a) { z0a = za[e]; e0a = e; }
  int e1a = (e0a == 0) ? 1 : 0; float z1a = za[e1a];
#pragma unroll
  for (int e = 0; e < NE; ++e) if (e != e0a && za[e] > z1a) { z1a = za[e]; e1a = e; }

  int e0b = 0; float z0b = zb[0];
#pragma unroll
  for (int e = 1; e < NE; ++e) if (zb[e] > z0b) { z0b = zb[e]; e0b = e; }
  int e1b = (e0b == 0) ? 1 : 0; float z1b = zb[e1b];
#pragma unroll
  for (int e = 0; e < NE; ++e) if (e != e0b && zb[e] > z1b) { z1b = zb[e]; e1b = e; }

  // normalized top-2 sigmoid probs
  float p0a = 1.f / (1.f + expf(-z0a));
  float p1a = 1.f / (1.f + expf(-z1a));
  float sa = 1.f / (p0a + p1a);
  float w0a = p0a * sa, w1a = p1a * sa;

  float p0b = 1.f / (1.f + expf(-z0b));
  float p1b = 1.f / (1.f + expf(-z1b));
  float sb = 1.f / (p0b + p1b);
  float w0b = p0b * sb, w1b = p1b * sb;

  // ---- only features o=0 (for j=0) and o=1 (for j=1) are needed ----
  const float4* ra0 = (const float4*)(expert_w + (size_t)e0a * (DOUT * DIN));
  const float4* ra1 = (const float4*)(expert_w + (size_t)e1a * (DOUT * DIN) + DIN);
  const float4* rb0 = (const float4*)(expert_w + (size_t)e0b * (DOUT * DIN));
  const float4* rb1 = (const float4*)(expert_w + (size_t)e1b * (DOUT * DIN) + DIN);

  float d0a = 0.f, d1a = 0.f, d0b = 0.f, d1b = 0.f;
#pragma unroll
  for (int i = 0; i < 4; ++i) {
    float4 wa0 = ra0[lane + 64 * i];
    float4 wa1 = ra1[lane + 64 * i];
    float4 wb0 = rb0[lane + 64 * i];
    float4 wb1 = rb1[lane + 64 * i];
    d0a += xa[i].x * wa0.x + xa[i].y * wa0.y + xa[i].z * wa0.z + xa[i].w * wa0.w;
    d1a += xa[i].x * wa1.x + xa[i].y * wa1.y + xa[i].z * wa1.z + xa[i].w * wa1.w;
    d0b += xb[i].x * wb0.x + xb[i].y * wb0.y + xb[i].z * wb0.z + xb[i].w * wb0.w;
    d1b += xb[i].x * wb1.x + xb[i].y * wb1.y + xb[i].z * wb1.z + xb[i].w * wb1.w;
  }
  d0a = wredsum(d0a) + expert_b[e0a * DOUT + 0];
  d1a = wredsum(d1a) + expert_b[e1a * DOUT + 1];
  d0b = wredsum(d0b) + expert_b[e0b * DOUT + 0];
  d1b = wredsum(d1b) + expert_b[e1b * DOUT + 1];

  float ova = d0a * w0a + d1a * w1a;
  float ovb = d0b * w0b + d1b * w1b;

  // ---- broadcast store: out[t,:] = weighted scalar ----
  float4 va = make_float4(ova, ova, ova, ova);
  float4 vb = make_float4(ovb, ovb, ovb, ovb);
  float4* oa = (float4*)(out + (size_t)t0 * DOUT);
  float4* ob = (float4*)(out + (size_t)t1 * DOUT);
#pragma unroll
  for (int i = 0; i < 4; ++i) {
    oa[lane + 64 * i] = va;
    ob[lane + 64 * i] = vb;
  }

  if (lane == 0) {
    out_idx[t0 * 2 + 0] = (float)e0a;
    out_idx[t0 * 2 + 1] = (float)e1a;
    out_idx[t1 * 2 + 0] = (float)e0b;
    out_idx[t1 * 2 + 1] = (float)e1b;
  }
}

extern "C" void kernel_launch(void* const* d_in, const int* in_sizes, int n_in,
                              void* d_out, int out_size, void* d_ws, size_t ws_size,
                              hipStream_t stream) {
  const float* x             = (const float*)d_in[0];
  const float* gate_w        = (const float*)d_in[1];
  const float* gate_b        = (const float*)d_in[2];
  const float* expert_biases = (const float*)d_in[3];
  const float* expert_w      = (const float*)d_in[4];
  const float* expert_b      = (const float*)d_in[5];

  float* out     = (float*)d_out;
  float* out_idx = out + (size_t)TOKENS * DOUT;  // second tuple output, flat-concatenated

  moe_fused<<<dim3(TOKENS / (4 * 2)), dim3(256), 0, stream>>>(
      x, gate_w, gate_b, expert_biases, expert_w, expert_b, out, out_idx);
}

// Round 3
// 119.635 us; speedup vs baseline: 1.0930x; 1.0930x over previous
//
#include <hip/hip_runtime.h>
#include <math.h>

// Problem constants: B=4, S=2048, D_IN=1024, D_OUT=1024, E=8, K=2
#define TOKENS 8192
#define DIN    1024
#define DOUT   1024
#define NE     8

typedef float vf4 __attribute__((ext_vector_type(4)));  // clang-native, OK for nontemporal builtins

// Butterfly reduction across the 64-lane wave; every lane ends with the full sum.
__device__ __forceinline__ float wredsum(float v) {
#pragma unroll
  for (int off = 32; off > 0; off >>= 1) v += __shfl_xor(v, off, 64);
  return v;
}

// One wave per token. 512-thread blocks (8 waves) share one 32 KB LDS copy of
// gate_w, so LDS/CU = 4 blocks x 32 KB = 128 KB <= 160 KB and occupancy is the
// full 32 waves/CU (VGPR<=64 enforced by launch_bounds). Grid: 8192/8 = 1024.
__global__ __launch_bounds__(512, 8) void moe_fused(
    const float* __restrict__ x,             // [TOKENS][DIN]
    const float* __restrict__ gate_w,        // [NE][DIN]
    const float* __restrict__ gate_b,        // [NE]
    const float* __restrict__ expert_biases, // [NE]
    const float* __restrict__ expert_w,      // [NE][DOUT][DIN]
    const float* __restrict__ expert_b,      // [NE][DOUT]
    float* __restrict__ out,                 // [TOKENS][DOUT]
    float* __restrict__ out_idx) {           // [TOKENS][2] (indices as f32)
  // ---- stage gate_w into LDS (32 KB), 2048 vf4 over 512 threads ----
  __shared__ float lgate[NE * DIN];
  {
    const vf4* src = (const vf4*)gate_w;
    vf4* dst = (vf4*)lgate;
#pragma unroll
    for (int i = 0; i < 4; ++i)
      dst[threadIdx.x + i * 512] = src[threadIdx.x + i * 512];
  }
  __syncthreads();

  const int t    = blockIdx.x * 8 + (threadIdx.x >> 6);  // token == wave id
  const int lane = threadIdx.x & 63;

  // ---- load x row (coalesced 16B/lane), non-temporal (read-once stream) ----
  vf4 xa[4];
  const vf4* xr = (const vf4*)(x + (size_t)t * DIN);
#pragma unroll
  for (int i = 0; i < 4; ++i) xa[i] = __builtin_nontemporal_load(&xr[lane + 64 * i]);

  // ---- gate logits: 8 dots against LDS-resident gate_w ----
  float za[NE];
#pragma unroll
  for (int e = 0; e < NE; ++e) za[e] = 0.f;
#pragma unroll
  for (int e = 0; e < NE; ++e) {
    const vf4* wr = (const vf4*)(lgate + e * DIN);
#pragma unroll
    for (int i = 0; i < 4; ++i) {
      vf4 w = wr[lane + 64 * i];
      za[e] += xa[i].x * w.x + xa[i].y * w.y + xa[i].z * w.z + xa[i].w * w.w;
    }
  }
#pragma unroll
  for (int e = 0; e < NE; ++e) za[e] = wredsum(za[e]) + gate_b[e] + expert_biases[e];

  // ---- top-2 on logits (sigmoid monotone -> identical indices & tie order) ----
  int e0 = 0; float z0 = za[0];
#pragma unroll
  for (int e = 1; e < NE; ++e) if (za[e] > z0) { z0 = za[e]; e0 = e; }
  int e1 = (e0 == 0) ? 1 : 0; float z1 = za[e1];
#pragma unroll
  for (int e = 0; e < NE; ++e) if (e != e0 && za[e] > z1) { z1 = za[e]; e1 = e; }

  float p0 = 1.f / (1.f + expf(-z0));
  float p1 = 1.f / (1.f + expf(-z1));
  float s  = 1.f / (p0 + p1);
  float w0 = p0 * s, w1 = p1 * s;

  // ---- only expert features o=0 (j=0) and o=1 (j=1) are ever gathered ----
  const vf4* r0 = (const vf4*)(expert_w + (size_t)e0 * (DOUT * DIN));
  const vf4* r1 = (const vf4*)(expert_w + (size_t)e1 * (DOUT * DIN) + DIN);
  float d0 = 0.f, d1 = 0.f;
#pragma unroll
  for (int i = 0; i < 4; ++i) {
    vf4 a = r0[lane + 64 * i];
    vf4 b = r1[lane + 64 * i];
    d0 += xa[i].x * a.x + xa[i].y * a.y + xa[i].z * a.z + xa[i].w * a.w;
    d1 += xa[i].x * b.x + xa[i].y * b.y + xa[i].z * b.z + xa[i].w * b.w;
  }
  d0 = wredsum(d0) + expert_b[e0 * DOUT + 0];
  d1 = wredsum(d1) + expert_b[e1 * DOUT + 1];

  float ov = d0 * w0 + d1 * w1;

  // ---- broadcast store: out[t,:] = weighted scalar (full 4 KB row / wave) ----
  vf4 v = {ov, ov, ov, ov};
  vf4* orow = (vf4*)(out + (size_t)t * DOUT);
#pragma unroll
  for (int i = 0; i < 4; ++i) orow[lane + 64 * i] = v;

  if (lane == 0) {
    out_idx[t * 2 + 0] = (float)e0;
    out_idx[t * 2 + 1] = (float)e1;
  }
}

extern "C" void kernel_launch(void* const* d_in, const int* in_sizes, int n_in,
                              void* d_out, int out_size, void* d_ws, size_t ws_size,
                              hipStream_t stream) {
  const float* x             = (const float*)d_in[0];
  const float* gate_w        = (const float*)d_in[1];
  const float* gate_b        = (const float*)d_in[2];
  const float* expert_biases = (const float*)d_in[3];
  const float* expert_w      = (const float*)d_in[4];
  const float* expert_b      = (const float*)d_in[5];

  float* out     = (float*)d_out;
  float* out_idx = out + (size_t)TOKENS * DOUT;  // second tuple output, flat-concatenated

  moe_fused<<<dim3(TOKENS / 8), dim3(512), 0, stream>>>(
      x, gate_w, gate_b, expert_biases, expert_w, expert_b, out, out_idx);
}